// Round 1
// baseline (144.219 us; speedup 1.0000x reference)
//
#include <hip/hip_runtime.h>

// C^4 for B independent 6x6 fp32 matrices: one thread per matrix.
// Memory-bound (576 MB total traffic vs ~1.7 GFLOP). All compute in regs.

__global__ __launch_bounds__(256) void matpow4_kernel(
    const float* __restrict__ C, float* __restrict__ out, int B)
{
    int idx = blockIdx.x * blockDim.x + threadIdx.x;
    if (idx >= B) return;

    const float4* src = reinterpret_cast<const float4*>(C + (size_t)idx * 36);
    float a[36];
#pragma unroll
    for (int k = 0; k < 9; ++k) {
        float4 v = src[k];
        a[4 * k + 0] = v.x;
        a[4 * k + 1] = v.y;
        a[4 * k + 2] = v.z;
        a[4 * k + 3] = v.w;
    }

    // C2 = C * C
    float b[36];
#pragma unroll
    for (int i = 0; i < 6; ++i) {
#pragma unroll
        for (int j = 0; j < 6; ++j) {
            float s = a[i * 6 + 0] * a[0 * 6 + j];
#pragma unroll
            for (int k = 1; k < 6; ++k)
                s = fmaf(a[i * 6 + k], a[k * 6 + j], s);
            b[i * 6 + j] = s;
        }
    }

    // C4 = C2 * C2  (reuse a[] as the destination; a is dead now)
#pragma unroll
    for (int i = 0; i < 6; ++i) {
#pragma unroll
        for (int j = 0; j < 6; ++j) {
            float s = b[i * 6 + 0] * b[0 * 6 + j];
#pragma unroll
            for (int k = 1; k < 6; ++k)
                s = fmaf(b[i * 6 + k], b[k * 6 + j], s);
            a[i * 6 + j] = s;
        }
    }

    float4* dst = reinterpret_cast<float4*>(out + (size_t)idx * 36);
#pragma unroll
    for (int k = 0; k < 9; ++k) {
        float4 v;
        v.x = a[4 * k + 0];
        v.y = a[4 * k + 1];
        v.z = a[4 * k + 2];
        v.w = a[4 * k + 3];
        dst[k] = v;
    }
}

extern "C" void kernel_launch(void* const* d_in, const int* in_sizes, int n_in,
                              void* d_out, int out_size, void* d_ws, size_t ws_size,
                              hipStream_t stream)
{
    const float* C = (const float*)d_in[0];
    float* out = (float*)d_out;
    int B = in_sizes[0] / 36;

    int block = 256;
    int grid = (B + block - 1) / block;
    matpow4_kernel<<<grid, block, 0, stream>>>(C, out, B);
}

// Round 2
// 117.672 us; speedup vs baseline: 1.2256x; 1.2256x over previous
//
#include <hip/hip_runtime.h>

// C^4 for B independent 6x6 fp32 matrices.
// Structure: block = 256 matrices. Coalesced float4 global loads -> LDS
// (pad-37 layout, conflict-free per-thread reads) -> per-thread C^4 in regs
// -> LDS -> coalesced float4 global stores.

#define MPB 256   // matrices per block
#define PAD 37    // 36 + 1, odd => stride-37 scalar LDS access conflict-free

__global__ __launch_bounds__(256, 4) void matpow4_kernel(
    const float* __restrict__ C, float* __restrict__ out, int B)
{
    __shared__ float lds[MPB * PAD];  // 37888 B

    const int tid = threadIdx.x;
    const long long mbase = (long long)blockIdx.x * MPB;
    const int nm = (int)min((long long)MPB, (long long)B - mbase);
    const int nf4 = nm * 9;  // float4 count this block

    const float4* __restrict__ src = reinterpret_cast<const float4*>(C) + mbase * 9;

    // 1) coalesced load + scatter into padded LDS
#pragma unroll
    for (int k = 0; k < 9; ++k) {
        int f = k * MPB + tid;
        if (f < nf4) {
            float4 v = src[f];
            int e = f * 4;            // flat element index within block
            int w = e + e / 36;       // padded word addr: m*37 + (e%36)
            lds[w + 0] = v.x;
            lds[w + 1] = v.y;
            lds[w + 2] = v.z;
            lds[w + 3] = v.w;
        }
    }
    __syncthreads();

    // 2) per-thread compute, own matrix from own LDS row
    float a[36], b[36];
    if (tid < nm) {
        const float* m = &lds[tid * PAD];
#pragma unroll
        for (int j = 0; j < 36; ++j) a[j] = m[j];

        // C2 = C*C
#pragma unroll
        for (int i = 0; i < 6; ++i) {
#pragma unroll
            for (int j = 0; j < 6; ++j) {
                float s = a[i * 6 + 0] * a[0 * 6 + j];
#pragma unroll
                for (int k = 1; k < 6; ++k)
                    s = fmaf(a[i * 6 + k], a[k * 6 + j], s);
                b[i * 6 + j] = s;
            }
        }
        // C4 = C2*C2 (into a; a dead)
#pragma unroll
        for (int i = 0; i < 6; ++i) {
#pragma unroll
            for (int j = 0; j < 6; ++j) {
                float s = b[i * 6 + 0] * b[0 * 6 + j];
#pragma unroll
                for (int k = 1; k < 6; ++k)
                    s = fmaf(b[i * 6 + k], b[k * 6 + j], s);
                a[i * 6 + j] = s;
            }
        }

        // 3) result back to own LDS row (no sync needed: region private since
        //    the pre-compute __syncthreads)
        float* mo = &lds[tid * PAD];
#pragma unroll
        for (int j = 0; j < 36; ++j) mo[j] = a[j];
    }
    __syncthreads();

    // 4) gather from padded LDS + coalesced store
    float4* __restrict__ dst = reinterpret_cast<float4*>(out) + mbase * 9;
#pragma unroll
    for (int k = 0; k < 9; ++k) {
        int f = k * MPB + tid;
        if (f < nf4) {
            int e = f * 4;
            int w = e + e / 36;
            float4 v;
            v.x = lds[w + 0];
            v.y = lds[w + 1];
            v.z = lds[w + 2];
            v.w = lds[w + 3];
            dst[f] = v;
        }
    }
}

extern "C" void kernel_launch(void* const* d_in, const int* in_sizes, int n_in,
                              void* d_out, int out_size, void* d_ws, size_t ws_size,
                              hipStream_t stream)
{
    const float* C = (const float*)d_in[0];
    float* out = (float*)d_out;
    int B = in_sizes[0] / 36;

    int grid = (B + MPB - 1) / MPB;
    matpow4_kernel<<<grid, MPB, 0, stream>>>(C, out, B);
}

// Round 3
// 110.134 us; speedup vs baseline: 1.3095x; 1.0684x over previous
//
#include <hip/hip_runtime.h>

// C^4 for B independent 6x6 fp32 matrices.
// Block = 256 matrices. Linear LDS layout (matrix = 9 contiguous float4,
// stride-9-float4 is odd => per-thread b128 access is bank-conflict-free).
// Phase 1: global_load_lds width=16 (async direct-to-LDS, linear dest).
// Phase 2: per-thread C^4 in regs via ds_read_b128 / ds_write_b128.
// Phase 3: dense gather + coalesced float4 global stores.

#define MPB 256   // matrices per block

#define GLOBAL_AS __attribute__((address_space(1)))
#define LDS_AS    __attribute__((address_space(3)))

__global__ __launch_bounds__(256, 4) void matpow4_kernel(
    const float* __restrict__ C, float* __restrict__ out, int B)
{
    __shared__ float4 lds4[MPB * 9];  // 36864 B

    const int tid = threadIdx.x;
    const long long mbase = (long long)blockIdx.x * MPB;
    const int nm = (int)min((long long)MPB, (long long)B - mbase);
    const int nf4 = nm * 9;  // float4 count this block

    const float4* __restrict__ src = reinterpret_cast<const float4*>(C) + mbase * 9;

    // 1) async global -> LDS, linear, perfectly coalesced, no VGPR roundtrip.
    //    Active lanes are a prefix of each wave, so the wave-uniform LDS base
    //    (first active lane) is correct even in the tail block.
#pragma unroll
    for (int k = 0; k < 9; ++k) {
        int f = k * MPB + tid;
        if (f < nf4) {
            __builtin_amdgcn_global_load_lds(
                (const GLOBAL_AS void*)(src + f),
                (LDS_AS void*)(&lds4[f]),
                16, 0, 0);
        }
    }
    __syncthreads();  // drains vmcnt before any LDS read

    // 2) per-thread compute; own matrix = 9 consecutive float4 at lds4[tid*9]
    if (tid < nm) {
        float a[36], b[36];
#pragma unroll
        for (int j = 0; j < 9; ++j) {
            float4 v = lds4[tid * 9 + j];   // ds_read_b128, conflict-free
            a[4 * j + 0] = v.x;
            a[4 * j + 1] = v.y;
            a[4 * j + 2] = v.z;
            a[4 * j + 3] = v.w;
        }

        // C2 = C*C
#pragma unroll
        for (int i = 0; i < 6; ++i) {
#pragma unroll
            for (int j = 0; j < 6; ++j) {
                float s = a[i * 6 + 0] * a[0 * 6 + j];
#pragma unroll
                for (int k = 1; k < 6; ++k)
                    s = fmaf(a[i * 6 + k], a[k * 6 + j], s);
                b[i * 6 + j] = s;
            }
        }
        // C4 = C2*C2 (into a; a dead)
#pragma unroll
        for (int i = 0; i < 6; ++i) {
#pragma unroll
            for (int j = 0; j < 6; ++j) {
                float s = b[i * 6 + 0] * b[0 * 6 + j];
#pragma unroll
                for (int k = 1; k < 6; ++k)
                    s = fmaf(b[i * 6 + k], b[k * 6 + j], s);
                a[i * 6 + j] = s;
            }
        }

        // write result back to own region (ds_write_b128, conflict-free;
        // region is thread-private since the barrier, so no extra sync here)
#pragma unroll
        for (int j = 0; j < 9; ++j) {
            float4 v;
            v.x = a[4 * j + 0];
            v.y = a[4 * j + 1];
            v.z = a[4 * j + 2];
            v.w = a[4 * j + 3];
            lds4[tid * 9 + j] = v;
        }
    }
    __syncthreads();

    // 3) dense gather + coalesced store
    float4* __restrict__ dst = reinterpret_cast<float4*>(out) + mbase * 9;
#pragma unroll
    for (int k = 0; k < 9; ++k) {
        int f = k * MPB + tid;
        if (f < nf4) {
            dst[f] = lds4[f];
        }
    }
}

extern "C" void kernel_launch(void* const* d_in, const int* in_sizes, int n_in,
                              void* d_out, int out_size, void* d_ws, size_t ws_size,
                              hipStream_t stream)
{
    const float* C = (const float*)d_in[0];
    float* out = (float*)d_out;
    int B = in_sizes[0] / 36;

    int grid = (B + MPB - 1) / MPB;
    matpow4_kernel<<<grid, MPB, 0, stream>>>(C, out, B);
}